// Round 11
// baseline (44.745 us; speedup 1.0000x reference)
//
#include <hip/hip_runtime.h>
#include <math.h>

#define N_ATOMS 4096
#define CUTOFF2 25.0f
#define NI_T    8                // i-tiles of 512
#define NJ      256              // j slices
#define JT      16               // j atoms per slice (8 pairs)
#define LOG2E   1.4426950408889634f
#define LN2     0.6931471805599453f

typedef float v2f __attribute__((ext_vector_type(2)));

__device__ __forceinline__ float pow20f(float t) {
    float t2 = t * t, t4 = t2 * t2, t8 = t4 * t4, t16 = t8 * t8;
    return t16 * t4;
}
__device__ __forceinline__ v2f pow20v(v2f t) {
    v2f t2 = t * t, t4 = t2 * t2, t8 = t4 * t4, t16 = t8 * t8;
    return t16 * t4;
}

// deterministic block reduction (256 threads); result broadcast via red[0..3]
__device__ __forceinline__ float block_reduce(float v, float* red) {
    __syncthreads();
    #pragma unroll
    for (int off = 32; off > 0; off >>= 1) v += __shfl_down(v, off, 64);
    if ((threadIdx.x & 63) == 0) red[threadIdx.x >> 6] = v;
    __syncthreads();
    return (red[0] + red[1]) + (red[2] + red[3]);
}

// K0: per-atom folded constants.
// apk[a] (4 float4 = 64 B/atom):
//   row0 {x,y,z,rei}  row1 {c0b, c1bp=b*log2e+log2(fe), mla, 0}
//   row2 {c0a, c1a=al2, mka, A}  row3 {Bof=B/fe, 0,0,0}
// rpk[pair] (4 float4): [x0,x1,y0,y1 | z0,z1,rei0,rei1 | c0b0,c0b1,c1bp0,c1bp1 | mla0,mla1,0,0]
__global__ __launch_bounds__(256) void pack_kernel(
    const float* __restrict__ coords, const float* __restrict__ params,
    float* __restrict__ apk, float* __restrict__ rpk)
{
    const int a = blockIdx.x * 256 + threadIdx.x;
    const float* p = params + 22 * a;
    const float x = coords[3*a], y = coords[3*a+1], z = coords[3*a+2];
    const float rei  = __builtin_amdgcn_rcpf(p[0]);
    const float bl2  = p[5] * LOG2E;
    const float al2  = p[4] * LOG2E;
    const float c0b  = -bl2 * rei;
    const float c1bp = bl2 + __builtin_amdgcn_logf(p[1]);   // log2(fe) folded
    const float c0a  = -al2 * rei;
    const float mla  = -p[9];

    float4* ad = (float4*)(apk + 16 * a);
    ad[0] = { x, y, z, rei };
    ad[1] = { c0b, c1bp, mla, 0.0f };
    ad[2] = { c0a, al2, -p[8], p[6] };
    ad[3] = { p[7] * __builtin_amdgcn_rcpf(p[1]), 0.0f, 0.0f, 0.0f };

    float* rd = rpk + 16 * (a >> 1) + (a & 1);
    rd[0] = x;   rd[2]  = y;    rd[4]  = z;   rd[6]  = rei;
    rd[8] = c0b; rd[10] = c1bp; rd[12] = mla; rd[14] = 0.0f;
}

// K1: rho + phi. grid (8,256) x 256. Thread owns i0 = bi*512+tid and i1 = i0+256.
// 4 ds_read_b128 per j-pair amortized over 2 i's; phi via ctz bitmask loop.
__global__ __launch_bounds__(256) void eam_main(
    const float* __restrict__ apk, const float* __restrict__ rpk,
    float* __restrict__ rho_part,    // [NJ][N_ATOMS]
    float* __restrict__ e_part)      // [NI_T*NJ]
{
    __shared__ float4 srho4[JT / 2 * 4];   // 32 float4 = 512 B
    __shared__ float4 sphi4[JT * 4];       // 64 float4 = 1 KB
    __shared__ float red[4];

    const int tid = threadIdx.x;
    const int bi  = blockIdx.x;        // 0..7
    const int s   = blockIdx.y;        // 0..255
    const int i0  = bi * 512 + tid;
    const int i1  = i0 + 256;
    const int jbase = s * JT;

    if (tid < 32)                    srho4[tid]      = ((const float4*)rpk)[s * 32 + tid];
    else if (tid >= 64 && tid < 128) sphi4[tid - 64] = ((const float4*)apk)[s * 64 + (tid - 64)];

    const float4* apk4 = (const float4*)apk;
    const float4 a00 = apk4[i0 * 4 + 0], a01 = apk4[i0 * 4 + 1];
    const float4 a02 = apk4[i0 * 4 + 2], a03 = apk4[i0 * 4 + 3];
    const float4 a10 = apk4[i1 * 4 + 0], a11 = apk4[i1 * 4 + 1];
    const float4 a12 = apk4[i1 * 4 + 2], a13 = apk4[i1 * 4 + 3];

    __syncthreads();

    const v2f xi0 = { a00.x, a00.x }, yi0 = { a00.y, a00.y }, zi0 = { a00.z, a00.z };
    const v2f xi1 = { a10.x, a10.x }, yi1 = { a10.y, a10.y }, zi1 = { a10.z, a10.z };

    v2f rho0v = { 0.0f, 0.0f }, rho1v = { 0.0f, 0.0f };
    unsigned int m0 = 0, m1 = 0;

    #pragma unroll
    for (int k = 0; k < JT / 2; ++k) {
        const float4 f0 = srho4[k * 4 + 0];   // x0,x1,y0,y1
        const float4 f1 = srho4[k * 4 + 1];   // z0,z1,rei0,rei1
        const float4 f2 = srho4[k * 4 + 2];   // c0b0,c0b1,c1bp0,c1bp1
        const float4 f3 = srho4[k * 4 + 3];   // mla0,mla1,-,-
        const v2f x01 = { f0.x, f0.y }, y01 = { f0.z, f0.w };
        const v2f z01 = { f1.x, f1.y }, rei01 = { f1.z, f1.w };
        const v2f c0b01 = { f2.x, f2.y }, c1b01 = { f2.z, f2.w };
        const v2f mla01 = { f3.x, f3.y };

        {   // i0
            const v2f dx = x01 - xi0, dy = y01 - yi0, dz = z01 - zi0;
            const v2f r2v = dx * dx + dy * dy + dz * dz;
            const v2f rv = { __builtin_amdgcn_sqrtf(r2v.x), __builtin_amdgcn_sqrtf(r2v.y) };
            const v2f ea = rv * c0b01 + c1b01;
            const v2f ev = { __builtin_amdgcn_exp2f(ea.x), __builtin_amdgcn_exp2f(ea.y) };
            const v2f pa = rv * rei01 + mla01;
            const v2f den = pow20v(pa) + 1.0f;
            const v2f dv = { __builtin_amdgcn_rcpf(den.x), __builtin_amdgcn_rcpf(den.y) };
            rho0v += ev * dv;
            if (r2v.x <= CUTOFF2) m0 |= (1u << (2 * k));
            if (r2v.y <= CUTOFF2) m0 |= (1u << (2 * k + 1));
        }
        {   // i1
            const v2f dx = x01 - xi1, dy = y01 - yi1, dz = z01 - zi1;
            const v2f r2v = dx * dx + dy * dy + dz * dz;
            const v2f rv = { __builtin_amdgcn_sqrtf(r2v.x), __builtin_amdgcn_sqrtf(r2v.y) };
            const v2f ea = rv * c0b01 + c1b01;
            const v2f ev = { __builtin_amdgcn_exp2f(ea.x), __builtin_amdgcn_exp2f(ea.y) };
            const v2f pa = rv * rei01 + mla01;
            const v2f den = pow20v(pa) + 1.0f;
            const v2f dv = { __builtin_amdgcn_rcpf(den.x), __builtin_amdgcn_rcpf(den.y) };
            rho1v += ev * dv;
            if (r2v.x <= CUTOFF2) m1 |= (1u << (2 * k));
            if (r2v.y <= CUTOFF2) m1 |= (1u << (2 * k + 1));
        }
    }

    float rho0 = rho0v.x + rho0v.y;
    float rho1 = rho1v.x + rho1v.y;
    if (i0 >= jbase && i0 < jbase + JT)
        rho0 -= __builtin_amdgcn_exp2f(a01.y) * __builtin_amdgcn_rcpf(1.0f + pow20f(a01.z));
    if (i1 >= jbase && i1 < jbase + JT)
        rho1 -= __builtin_amdgcn_exp2f(a11.y) * __builtin_amdgcn_rcpf(1.0f + pow20f(a11.z));
    rho_part[(size_t)s * N_ATOMS + i0] = rho0;
    rho_part[(size_t)s * N_ATOMS + i1] = rho1;

    // j > i exclusion (pair counted once)
    {
        const int t0 = i0 - jbase;
        if (t0 >= JT - 1)  m0 = 0u;
        else if (t0 >= 0)  m0 &= ~((2u << t0) - 1u);
        const int t1 = i1 - jbase;
        if (t1 >= JT - 1)  m1 = 0u;
        else if (t1 >= 0)  m1 &= ~((2u << t1) - 1u);
    }

    float e = 0.0f;
    while (m0) {
        const int k = __builtin_ctz(m0);
        m0 &= m0 - 1;
        const float4 q0 = sphi4[k * 4 + 0];
        const float4 q1 = sphi4[k * 4 + 1];
        const float4 q2 = sphi4[k * 4 + 2];
        const float Bof_j = sphi4[k * 4 + 3].x;
        const float dx = q0.x - a00.x, dy = q0.y - a00.y, dz = q0.z - a00.z;
        const float r = __builtin_amdgcn_sqrtf(fmaf(dx, dx, fmaf(dy, dy, dz * dz)));
        const float fri = __builtin_amdgcn_exp2f(fmaf(r, a01.x, a01.y))
                        * __builtin_amdgcn_rcpf(1.0f + pow20f(fmaf(r, a00.w, a01.z)));
        const float frj = __builtin_amdgcn_exp2f(fmaf(r, q1.x, q1.y))
                        * __builtin_amdgcn_rcpf(1.0f + pow20f(fmaf(r, q0.w, q1.z)));
        const float ph_i = a02.w * __builtin_amdgcn_exp2f(fmaf(r, a02.x, a02.y))
                                 * __builtin_amdgcn_rcpf(1.0f + pow20f(fmaf(r, a00.w, a02.z)))
                         - a03.x * fri;
        const float ph_j = q2.w * __builtin_amdgcn_exp2f(fmaf(r, q2.x, q2.y))
                                * __builtin_amdgcn_rcpf(1.0f + pow20f(fmaf(r, q0.w, q2.z)))
                         - Bof_j * frj;
        e += 0.5f * fmaf(frj * frj, ph_i, fri * fri * ph_j)
                  * __builtin_amdgcn_rcpf(fri * frj);
    }
    while (m1) {
        const int k = __builtin_ctz(m1);
        m1 &= m1 - 1;
        const float4 q0 = sphi4[k * 4 + 0];
        const float4 q1 = sphi4[k * 4 + 1];
        const float4 q2 = sphi4[k * 4 + 2];
        const float Bof_j = sphi4[k * 4 + 3].x;
        const float dx = q0.x - a10.x, dy = q0.y - a10.y, dz = q0.z - a10.z;
        const float r = __builtin_amdgcn_sqrtf(fmaf(dx, dx, fmaf(dy, dy, dz * dz)));
        const float fri = __builtin_amdgcn_exp2f(fmaf(r, a11.x, a11.y))
                        * __builtin_amdgcn_rcpf(1.0f + pow20f(fmaf(r, a10.w, a11.z)));
        const float frj = __builtin_amdgcn_exp2f(fmaf(r, q1.x, q1.y))
                        * __builtin_amdgcn_rcpf(1.0f + pow20f(fmaf(r, q0.w, q1.z)));
        const float ph_i = a12.w * __builtin_amdgcn_exp2f(fmaf(r, a12.x, a12.y))
                                 * __builtin_amdgcn_rcpf(1.0f + pow20f(fmaf(r, a10.w, a12.z)))
                         - a13.x * fri;
        const float ph_j = q2.w * __builtin_amdgcn_exp2f(fmaf(r, q2.x, q2.y))
                                * __builtin_amdgcn_rcpf(1.0f + pow20f(fmaf(r, q0.w, q2.z)))
                         - Bof_j * frj;
        e += 0.5f * fmaf(frj * frj, ph_i, fri * fri * ph_j)
                  * __builtin_amdgcn_rcpf(fri * frj);
    }

    const float eb = block_reduce(e, red);
    if (tid == 0) e_part[bi * NJ + s] = eb;
}

// K2: embed + partial e sums. 16 blocks x 256 threads.
__global__ __launch_bounds__(256) void eam_embed(
    const float* __restrict__ params,
    const float* __restrict__ rho_part, const float* __restrict__ e_part,
    float* __restrict__ tile_sum)    // [16]
{
    __shared__ float red[4];
    const int tid = threadIdx.x;
    const int b   = blockIdx.x;
    const int i   = b * 256 + tid;

    float s0 = 0.0f, s1 = 0.0f, s2 = 0.0f, s3 = 0.0f;
    #pragma unroll 8
    for (int t = 0; t < NJ; t += 4) {
        s0 += rho_part[(size_t)(t + 0) * N_ATOMS + i];
        s1 += rho_part[(size_t)(t + 1) * N_ATOMS + i];
        s2 += rho_part[(size_t)(t + 2) * N_ATOMS + i];
        s3 += rho_part[(size_t)(t + 3) * N_ATOMS + i];
    }
    const float rhoi = (s0 + s1) + (s2 + s3);

    const float* p = params + 22 * i;
    float F;
    if (rhoi < p[20]) {
        const float xn = rhoi / p[20] - 1.0f;
        F = p[10] + xn * (p[11] + xn * (p[12] + xn * p[13]));
    } else if (rhoi < p[21]) {
        const float xe = rhoi / p[2] - 1.0f;
        F = p[14] + xe * (p[15] + xe * (p[16] + xe * p[17]));
    } else {
        const float l2 = __builtin_amdgcn_logf(rhoi / p[3]);   // log2
        const float t  = __builtin_amdgcn_exp2f(p[18] * l2);
        const float lt = p[18] * l2 * LN2;                     // ln
        F = p[19] * (1.0f - lt) * t;
    }

    // e_part has NI_T*NJ = 2048 entries; each of 16 blocks sums a 128-chunk
    float acc = F + ((tid < 128) ? e_part[b * 128 + tid] : 0.0f);
    const float tot = block_reduce(acc, red);
    if (tid == 0) tile_sum[b] = tot;
}

// K3: final fixed-order sum of 16 partials (single wave)
__global__ __launch_bounds__(64) void eam_final(
    const float* __restrict__ tile_sum, float* __restrict__ out)
{
    const int tid = threadIdx.x;
    float acc = (tid < 16) ? tile_sum[tid] : 0.0f;
    #pragma unroll
    for (int off = 8; off > 0; off >>= 1) acc += __shfl_down(acc, off, 64);
    if (tid == 0) out[0] = acc;
}

extern "C" void kernel_launch(void* const* d_in, const int* in_sizes, int n_in,
                              void* d_out, int out_size, void* d_ws, size_t ws_size,
                              hipStream_t stream) {
    const float* coords = (const float*)d_in[0];   // [4096][3]
    const float* params = (const float*)d_in[1];   // [4096][22]
    float* out = (float*)d_out;

    float* apk      = (float*)d_ws;                          // [4096][16]
    float* rpk      = apk + (size_t)N_ATOMS * 16;            // [2048][16]
    float* rho_part = rpk + (size_t)(N_ATOMS / 2) * 16;      // [256][4096]
    float* e_part   = rho_part + (size_t)NJ * N_ATOMS;       // [2048]
    float* tile_sum = e_part + NI_T * NJ;                    // [16]

    pack_kernel<<<N_ATOMS / 256, 256, 0, stream>>>(coords, params, apk, rpk);
    dim3 grid(NI_T, NJ);
    eam_main<<<grid, 256, 0, stream>>>(apk, rpk, rho_part, e_part);
    eam_embed<<<16, 256, 0, stream>>>(params, rho_part, e_part, tile_sum);
    eam_final<<<1, 64, 0, stream>>>(tile_sum, out);
}

// Round 12
// 32.042 us; speedup vs baseline: 1.3964x; 1.3964x over previous
//
#include <hip/hip_runtime.h>
#include <math.h>

#define N_ATOMS 4096
#define CUTOFF2 25.0f
#define NI_T    8                // i-tiles of 512 (2 atoms per thread)
#define NJ      128              // j slices
#define JT      32               // j atoms per slice
#define LOG2E   1.4426950408889634f
#define LN2     0.6931471805599453f

typedef float v2f __attribute__((ext_vector_type(2)));

__device__ __forceinline__ float pow20f(float t) {
    float t2 = t * t, t4 = t2 * t2, t8 = t4 * t4, t16 = t8 * t8;
    return t16 * t4;
}
__device__ __forceinline__ v2f pow20v(v2f t) {
    v2f t2 = t * t, t4 = t2 * t2, t8 = t4 * t4, t16 = t8 * t8;
    return t16 * t4;
}

// deterministic block reduction (256 threads); result broadcast via red[0..3]
__device__ __forceinline__ float block_reduce(float v, float* red) {
    __syncthreads();
    #pragma unroll
    for (int off = 32; off > 0; off >>= 1) v += __shfl_down(v, off, 64);
    if ((threadIdx.x & 63) == 0) red[threadIdx.x >> 6] = v;
    __syncthreads();
    return (red[0] + red[1]) + (red[2] + red[3]);
}

// K1: rho + phi fused, Mi=2. grid (8,128) x 256. Thread owns i0=bi*512+tid, i1=i0+256.
// Slice (32 j) constants packed in-block to LDS (R10 structure); 4 ds_read_b128
// per j-pair amortized over BOTH i's; phi via ctz bitmask loops.
__global__ __launch_bounds__(256, 4) void eam_main(
    const float* __restrict__ coords, const float* __restrict__ params,
    float* __restrict__ rho_part,    // [NJ][N_ATOMS]
    float* __restrict__ e_part)      // [NI_T*NJ]
{
    // srho: 16 pairs x [x0,x1,y0,y1 | z0,z1,rei0,rei1 | c0b0,c0b1,c1bp0,c1bp1 | mla0,mla1,-,-]
    __shared__ float srho[16 * 16];          // 1 KB
    // sphi: 32 atoms x [x,y,z,rei | c0b,c1bp,mla,0 | c0a,c1a,mka,A | Bof,-,-,-]
    __shared__ float sphi[JT * 16];          // 2 KB
    __shared__ float red[4];

    const int tid = threadIdx.x;
    const int bi  = blockIdx.x;      // 0..7
    const int s   = blockIdx.y;      // 0..127
    const int i0  = bi * 512 + tid;
    const int i1  = i0 + 256;
    const int jbase = s * JT;

    if (tid < JT) {   // pack slice atom jbase+tid into LDS (R10-proven)
        const int j = jbase + tid;
        const float* p = params + 22 * j;
        const float x = coords[3*j], y = coords[3*j+1], z = coords[3*j+2];
        const float rei  = __builtin_amdgcn_rcpf(p[0]);
        const float bl2  = p[5] * LOG2E;
        const float al2  = p[4] * LOG2E;
        const float c0b  = -bl2 * rei;
        const float c1bp = bl2 + __builtin_amdgcn_logf(p[1]);   // log2(fe) folded
        const float c0a  = -al2 * rei;
        const float mla  = -p[9];

        float* ph = sphi + 16 * tid;
        ph[0] = x;    ph[1] = y;    ph[2]  = z;     ph[3]  = rei;
        ph[4] = c0b;  ph[5] = c1bp; ph[6]  = mla;   ph[7]  = 0.0f;
        ph[8] = c0a;  ph[9] = al2;  ph[10] = -p[8]; ph[11] = p[6];
        ph[12] = p[7] * __builtin_amdgcn_rcpf(p[1]);            // Bof = B/fe

        float* rd = srho + 16 * (tid >> 1) + (tid & 1);
        rd[0] = x;   rd[2]  = y;    rd[4]  = z;   rd[6]  = rei;
        rd[8] = c0b; rd[10] = c1bp; rd[12] = mla;
    }

    // i-side constants for both atoms
    const float* p0 = params + 22 * i0;
    const float x0 = coords[3*i0], y0 = coords[3*i0+1], z0 = coords[3*i0+2];
    const float rei_0  = __builtin_amdgcn_rcpf(p0[0]);
    const float bl2_0  = p0[5] * LOG2E;
    const float al2_0  = p0[4] * LOG2E;
    const float c0b_0  = -bl2_0 * rei_0;
    const float c1bp_0 = bl2_0 + __builtin_amdgcn_logf(p0[1]);
    const float c0a_0  = -al2_0 * rei_0;
    const float mla_0  = -p0[9];
    const float mka_0  = -p0[8];
    const float A_0    = p0[6];
    const float Bof_0  = p0[7] * __builtin_amdgcn_rcpf(p0[1]);

    const float* p1 = params + 22 * i1;
    const float x1 = coords[3*i1], y1 = coords[3*i1+1], z1 = coords[3*i1+2];
    const float rei_1  = __builtin_amdgcn_rcpf(p1[0]);
    const float bl2_1  = p1[5] * LOG2E;
    const float al2_1  = p1[4] * LOG2E;
    const float c0b_1  = -bl2_1 * rei_1;
    const float c1bp_1 = bl2_1 + __builtin_amdgcn_logf(p1[1]);
    const float c0a_1  = -al2_1 * rei_1;
    const float mla_1  = -p1[9];
    const float mka_1  = -p1[8];
    const float A_1    = p1[6];
    const float Bof_1  = p1[7] * __builtin_amdgcn_rcpf(p1[1]);

    __syncthreads();

    const v2f xi0 = { x0, x0 }, yi0 = { y0, y0 }, zi0 = { z0, z0 };
    const v2f xi1 = { x1, x1 }, yi1 = { y1, y1 }, zi1 = { z1, z1 };
    v2f rho0v = { 0.0f, 0.0f }, rho1v = { 0.0f, 0.0f };
    unsigned int m0 = 0, m1 = 0;

    const float4* sp4 = (const float4*)srho;
    #pragma unroll 4
    for (int k = 0; k < JT / 2; ++k) {
        const float4 f0 = sp4[k * 4 + 0];   // x0,x1,y0,y1
        const float4 f1 = sp4[k * 4 + 1];   // z0,z1,rei0,rei1
        const float4 f2 = sp4[k * 4 + 2];   // c0b0,c0b1,c1bp0,c1bp1
        const float4 f3 = sp4[k * 4 + 3];   // mla0,mla1,-,-
        const v2f x01 = { f0.x, f0.y }, y01 = { f0.z, f0.w };
        const v2f z01 = { f1.x, f1.y }, rei01 = { f1.z, f1.w };
        const v2f c0b01 = { f2.x, f2.y }, c1b01 = { f2.z, f2.w };
        const v2f mla01 = { f3.x, f3.y };

        {   // i0
            const v2f dx = x01 - xi0, dy = y01 - yi0, dz = z01 - zi0;
            const v2f r2v = dx * dx + dy * dy + dz * dz;
            const v2f rv = { __builtin_amdgcn_sqrtf(r2v.x), __builtin_amdgcn_sqrtf(r2v.y) };
            const v2f ea = rv * c0b01 + c1b01;
            const v2f ev = { __builtin_amdgcn_exp2f(ea.x), __builtin_amdgcn_exp2f(ea.y) };
            const v2f pa = rv * rei01 + mla01;
            const v2f den = pow20v(pa) + 1.0f;
            const v2f dv = { __builtin_amdgcn_rcpf(den.x), __builtin_amdgcn_rcpf(den.y) };
            rho0v += ev * dv;
            if (r2v.x <= CUTOFF2) m0 |= (1u << (2 * k));
            if (r2v.y <= CUTOFF2) m0 |= (1u << (2 * k + 1));
        }
        {   // i1
            const v2f dx = x01 - xi1, dy = y01 - yi1, dz = z01 - zi1;
            const v2f r2v = dx * dx + dy * dy + dz * dz;
            const v2f rv = { __builtin_amdgcn_sqrtf(r2v.x), __builtin_amdgcn_sqrtf(r2v.y) };
            const v2f ea = rv * c0b01 + c1b01;
            const v2f ev = { __builtin_amdgcn_exp2f(ea.x), __builtin_amdgcn_exp2f(ea.y) };
            const v2f pa = rv * rei01 + mla01;
            const v2f den = pow20v(pa) + 1.0f;
            const v2f dv = { __builtin_amdgcn_rcpf(den.x), __builtin_amdgcn_rcpf(den.y) };
            rho1v += ev * dv;
            if (r2v.x <= CUTOFF2) m1 |= (1u << (2 * k));
            if (r2v.y <= CUTOFF2) m1 |= (1u << (2 * k + 1));
        }
    }

    float rho0 = rho0v.x + rho0v.y;
    float rho1 = rho1v.x + rho1v.y;
    if (i0 >= jbase && i0 < jbase + JT)
        rho0 -= __builtin_amdgcn_exp2f(c1bp_0) * __builtin_amdgcn_rcpf(1.0f + pow20f(mla_0));
    if (i1 >= jbase && i1 < jbase + JT)
        rho1 -= __builtin_amdgcn_exp2f(c1bp_1) * __builtin_amdgcn_rcpf(1.0f + pow20f(mla_1));
    rho_part[(size_t)s * N_ATOMS + i0] = rho0;
    rho_part[(size_t)s * N_ATOMS + i1] = rho1;

    // j > i exclusion (pair counted once)
    {
        const int t0 = i0 - jbase;
        if (t0 >= JT - 1)  m0 = 0u;
        else if (t0 >= 0)  m0 &= ~((2u << t0) - 1u);
        const int t1 = i1 - jbase;
        if (t1 >= JT - 1)  m1 = 0u;
        else if (t1 >= 0)  m1 &= ~((2u << t1) - 1u);
    }

    float e = 0.0f;
    while (m0) {
        const int k = __builtin_ctz(m0);
        m0 &= m0 - 1;
        const float4 q0 = *(const float4*)&sphi[k * 16];
        const float4 q1 = *(const float4*)&sphi[k * 16 + 4];
        const float4 q2 = *(const float4*)&sphi[k * 16 + 8];
        const float Bof_j = sphi[k * 16 + 12];
        const float dx = q0.x - x0, dy = q0.y - y0, dz = q0.z - z0;
        const float r = __builtin_amdgcn_sqrtf(fmaf(dx, dx, fmaf(dy, dy, dz * dz)));
        const float fri = __builtin_amdgcn_exp2f(fmaf(r, c0b_0, c1bp_0))
                        * __builtin_amdgcn_rcpf(1.0f + pow20f(fmaf(r, rei_0, mla_0)));
        const float frj = __builtin_amdgcn_exp2f(fmaf(r, q1.x, q1.y))
                        * __builtin_amdgcn_rcpf(1.0f + pow20f(fmaf(r, q0.w, q1.z)));
        const float ph_i = A_0 * __builtin_amdgcn_exp2f(fmaf(r, c0a_0, al2_0))
                               * __builtin_amdgcn_rcpf(1.0f + pow20f(fmaf(r, rei_0, mka_0)))
                         - Bof_0 * fri;
        const float ph_j = q2.w * __builtin_amdgcn_exp2f(fmaf(r, q2.x, q2.y))
                                * __builtin_amdgcn_rcpf(1.0f + pow20f(fmaf(r, q0.w, q2.z)))
                         - Bof_j * frj;
        e += 0.5f * fmaf(frj * frj, ph_i, fri * fri * ph_j)
                  * __builtin_amdgcn_rcpf(fri * frj);
    }
    while (m1) {
        const int k = __builtin_ctz(m1);
        m1 &= m1 - 1;
        const float4 q0 = *(const float4*)&sphi[k * 16];
        const float4 q1 = *(const float4*)&sphi[k * 16 + 4];
        const float4 q2 = *(const float4*)&sphi[k * 16 + 8];
        const float Bof_j = sphi[k * 16 + 12];
        const float dx = q0.x - x1, dy = q0.y - y1, dz = q0.z - z1;
        const float r = __builtin_amdgcn_sqrtf(fmaf(dx, dx, fmaf(dy, dy, dz * dz)));
        const float fri = __builtin_amdgcn_exp2f(fmaf(r, c0b_1, c1bp_1))
                        * __builtin_amdgcn_rcpf(1.0f + pow20f(fmaf(r, rei_1, mla_1)));
        const float frj = __builtin_amdgcn_exp2f(fmaf(r, q1.x, q1.y))
                        * __builtin_amdgcn_rcpf(1.0f + pow20f(fmaf(r, q0.w, q1.z)));
        const float ph_i = A_1 * __builtin_amdgcn_exp2f(fmaf(r, c0a_1, al2_1))
                               * __builtin_amdgcn_rcpf(1.0f + pow20f(fmaf(r, rei_1, mka_1)))
                         - Bof_1 * fri;
        const float ph_j = q2.w * __builtin_amdgcn_exp2f(fmaf(r, q2.x, q2.y))
                                * __builtin_amdgcn_rcpf(1.0f + pow20f(fmaf(r, q0.w, q2.z)))
                         - Bof_j * frj;
        e += 0.5f * fmaf(frj * frj, ph_i, fri * fri * ph_j)
                  * __builtin_amdgcn_rcpf(fri * frj);
    }

    const float eb = block_reduce(e, red);
    if (tid == 0) e_part[bi * NJ + s] = eb;
}

// K2: embed + per-tile e reduction. 16 blocks x 256 threads.
__global__ __launch_bounds__(256) void eam_embed(
    const float* __restrict__ params,
    const float* __restrict__ rho_part, const float* __restrict__ e_part,
    float* __restrict__ tile_sum)    // [16]
{
    __shared__ float red[4];
    const int tid = threadIdx.x;
    const int b   = blockIdx.x;
    const int i   = b * 256 + tid;

    float s0 = 0.0f, s1 = 0.0f, s2 = 0.0f, s3 = 0.0f;
    #pragma unroll 8
    for (int t = 0; t < NJ; t += 4) {   // coalesced per slice
        s0 += rho_part[(size_t)(t + 0) * N_ATOMS + i];
        s1 += rho_part[(size_t)(t + 1) * N_ATOMS + i];
        s2 += rho_part[(size_t)(t + 2) * N_ATOMS + i];
        s3 += rho_part[(size_t)(t + 3) * N_ATOMS + i];
    }
    const float rhoi = (s0 + s1) + (s2 + s3);

    const float* p = params + 22 * i;
    float F;
    if (rhoi < p[20]) {
        const float xn = rhoi / p[20] - 1.0f;
        F = p[10] + xn * (p[11] + xn * (p[12] + xn * p[13]));
    } else if (rhoi < p[21]) {
        const float xe = rhoi / p[2] - 1.0f;
        F = p[14] + xe * (p[15] + xe * (p[16] + xe * p[17]));
    } else {
        const float l2 = __builtin_amdgcn_logf(rhoi / p[3]);   // log2
        const float t  = __builtin_amdgcn_exp2f(p[18] * l2);
        const float lt = p[18] * l2 * LN2;                     // ln
        F = p[19] * (1.0f - lt) * t;
    }

    // e_part has NI_T*NJ = 1024 entries; each of 16 blocks sums a 64-chunk
    float acc = F + ((tid < 64) ? e_part[b * 64 + tid] : 0.0f);
    const float tot = block_reduce(acc, red);
    if (tid == 0) tile_sum[b] = tot;
}

// K3: final fixed-order sum of 16 tile sums (single wave)
__global__ __launch_bounds__(64) void eam_final(
    const float* __restrict__ tile_sum, float* __restrict__ out)
{
    const int tid = threadIdx.x;
    float acc = (tid < 16) ? tile_sum[tid] : 0.0f;
    #pragma unroll
    for (int off = 8; off > 0; off >>= 1) acc += __shfl_down(acc, off, 64);
    if (tid == 0) out[0] = acc;
}

extern "C" void kernel_launch(void* const* d_in, const int* in_sizes, int n_in,
                              void* d_out, int out_size, void* d_ws, size_t ws_size,
                              hipStream_t stream) {
    const float* coords = (const float*)d_in[0];   // [4096][3]
    const float* params = (const float*)d_in[1];   // [4096][22]
    float* out = (float*)d_out;

    float* rho_part = (float*)d_ws;                          // [128][4096]
    float* e_part   = rho_part + (size_t)NJ * N_ATOMS;       // [1024]
    float* tile_sum = e_part + NI_T * NJ;                    // [16]

    dim3 grid(NI_T, NJ);
    eam_main<<<grid, 256, 0, stream>>>(coords, params, rho_part, e_part);
    eam_embed<<<16, 256, 0, stream>>>(params, rho_part, e_part, tile_sum);
    eam_final<<<1, 64, 0, stream>>>(tile_sum, out);
}